// Round 1
// baseline (6525.510 us; speedup 1.0000x reference)
//
#include <hip/hip_runtime.h>
#include <math.h>

// Problem dims
#define T_LEN 128
#define B_SZ  64
#define AD    32
#define ZD    64
#define KMIX  16
#define HID   128

// ---------------- workspace layout (floats) ----------------
#define WS_WT0IH 0          // [32][512]
#define WS_WT0HH 16384      // [128][512]
#define WS_WT1IH 81920      // [128][512]
#define WS_WT1HH 147456     // [128][512]
#define WS_B0    212992     // [512] bih0+bhh0
#define WS_B1    213504     // [512]
#define WS_Q     214016     // [64][64]
#define WS_R     218112     // [32][32]
#define WS_W     219136     // [T][B][16] mixture weights
#define WS_TOTAL 350208     // floats (~1.4 MB)

// ---------------- output layout (floats) ----------------
#define OUT_MEANS   0
#define OUT_COVS    524288
#define OUT_NMEANS  34078720
#define OUT_NCOVS   34603008
#define OUT_MATA    68157440
#define OUT_MATC    101711872
// total 118489088 floats

__device__ __forceinline__ float sigmoidf_(float x){ return 1.0f/(1.0f + expf(-x)); }

// ============ prep: transpose LSTM weights, fold biases, Q=QL QL^T+eps, R=RL RL^T+eps ============
__global__ __launch_bounds__(256) void prep_kernel(
    const float* __restrict__ Wih0, const float* __restrict__ Whh0,
    const float* __restrict__ bih0, const float* __restrict__ bhh0,
    const float* __restrict__ Wih1, const float* __restrict__ Whh1,
    const float* __restrict__ bih1, const float* __restrict__ bhh1,
    const float* __restrict__ QL,   const float* __restrict__ RL,
    float* __restrict__ ws)
{
  int idx = blockIdx.x*256 + threadIdx.x;
  if (idx < 16384) {                      // WT0ih[k*512+g] = Wih0[g*32+k]
    int g = idx & 511, k = idx >> 9;
    ws[WS_WT0IH + idx] = Wih0[g*32 + k];
  } else if (idx < 81920) {
    int e = idx - 16384; int g = e & 511, k = e >> 9;
    ws[WS_WT0HH + e] = Whh0[g*128 + k];
  } else if (idx < 147456) {
    int e = idx - 81920; int g = e & 511, k = e >> 9;
    ws[WS_WT1IH + e] = Wih1[g*128 + k];
  } else if (idx < 212992) {
    int e = idx - 147456; int g = e & 511, k = e >> 9;
    ws[WS_WT1HH + e] = Whh1[g*128 + k];
  } else if (idx < 213504) {
    int g = idx - 212992; ws[WS_B0 + g] = bih0[g] + bhh0[g];
  } else if (idx < 214016) {
    int g = idx - 213504; ws[WS_B1 + g] = bih1[g] + bhh1[g];
  } else if (idx < 218112) {              // Q
    int e = idx - 214016; int i = e >> 6, j = e & 63;
    float s = (i==j) ? 1e-3f : 0.f;
    for (int k = 0; k < 64; ++k) s += QL[i*64+k]*QL[j*64+k];
    ws[WS_Q + e] = s;
  } else if (idx < 219136) {              // R
    int e = idx - 218112; int i = e >> 5, j = e & 31;
    float s = (i==j) ? 1e-3f : 0.f;
    for (int k = 0; k < 32; ++k) s += RL[i*32+k]*RL[j*32+k];
    ws[WS_R + e] = s;
  }
}

// ============ 2-layer LSTM + softmax head -> w[T][B][16] ============
// grid: B blocks; 512 threads (one per gate). Threads 0..127 own c0/c1.
__global__ __launch_bounds__(512) void lstm_kernel(
    const float* __restrict__ as_, const float* __restrict__ ws,
    const float* __restrict__ linW, const float* __restrict__ linb,
    float* __restrict__ wout)
{
  const int b = blockIdx.x, tid = threadIdx.x;
  const float* WT0ih = ws + WS_WT0IH;
  const float* WT0hh = ws + WS_WT0HH;
  const float* WT1ih = ws + WS_WT1IH;
  const float* WT1hh = ws + WS_WT1HH;

  __shared__ float xs[32];
  __shared__ float h0[128];
  __shared__ float h1[128];
  __shared__ float gbuf[512];
  __shared__ float lg[16];

  float c0 = 0.f, c1 = 0.f;
  if (tid < 128) { h0[tid] = 0.f; h1[tid] = 0.f; }
  const float bias0 = ws[WS_B0 + tid];
  const float bias1 = ws[WS_B1 + tid];
  __syncthreads();

  for (int t = 0; t < T_LEN; ++t) {
    if (tid < 32) xs[tid] = as_[(t*B_SZ + b)*AD + tid];
    __syncthreads();
    // layer 0 gates
    {
      float acc = bias0;
      #pragma unroll 8
      for (int k = 0; k < 32; ++k)  acc += WT0ih[k*512 + tid] * xs[k];
      #pragma unroll 8
      for (int k = 0; k < 128; ++k) acc += WT0hh[k*512 + tid] * h0[k];
      gbuf[tid] = acc;
    }
    __syncthreads();
    if (tid < 128) {
      float ig = sigmoidf_(gbuf[tid]);
      float fg = sigmoidf_(gbuf[tid+128]);
      float gg = tanhf(gbuf[tid+256]);
      float og = sigmoidf_(gbuf[tid+384]);
      c0 = fg*c0 + ig*gg;
      h0[tid] = og * tanhf(c0);
    }
    __syncthreads();
    // layer 1 gates
    {
      float acc = bias1;
      #pragma unroll 8
      for (int k = 0; k < 128; ++k) acc += WT1ih[k*512 + tid] * h0[k];
      #pragma unroll 8
      for (int k = 0; k < 128; ++k) acc += WT1hh[k*512 + tid] * h1[k];
      gbuf[tid] = acc;
    }
    __syncthreads();
    if (tid < 128) {
      float ig = sigmoidf_(gbuf[tid]);
      float fg = sigmoidf_(gbuf[tid+128]);
      float gg = tanhf(gbuf[tid+256]);
      float og = sigmoidf_(gbuf[tid+384]);
      c1 = fg*c1 + ig*gg;
      h1[tid] = og * tanhf(c1);
    }
    __syncthreads();
    if (tid < 16) {
      float acc = linb[tid];
      #pragma unroll 8
      for (int k = 0; k < 128; ++k) acc += linW[tid*128 + k] * h1[k];
      lg[tid] = acc;
    }
    __syncthreads();
    if (tid == 0) {
      float m = lg[0];
      #pragma unroll
      for (int k = 1; k < 16; ++k) m = fmaxf(m, lg[k]);
      float e[16]; float s = 0.f;
      #pragma unroll
      for (int k = 0; k < 16; ++k) { e[k] = expf(lg[k] - m); s += e[k]; }
      float inv = 1.f / s;
      #pragma unroll
      for (int k = 0; k < 16; ++k) wout[(t*B_SZ + b)*KMIX + k] = e[k]*inv;
    }
    __syncthreads();
  }
}

// ============ mix: mat_As/mat_Cs = sum_k w_k * {A_K,C_K}[k] ============
// grid: (T*B)/16 blocks; each block does 16 consecutive (t,b) pairs to reuse A_K/C_K reads.
__global__ __launch_bounds__(256) void mix_kernel(
    const float* __restrict__ w, const float* __restrict__ AK,
    const float* __restrict__ CK, float* __restrict__ out)
{
  float* matA = out + OUT_MATA;
  float* matC = out + OUT_MATC;
  const int tb0 = blockIdx.x * 16;
  const int tid = threadIdx.x;
  __shared__ float wl[16][16];
  { int lt = tid >> 4, k = tid & 15; wl[lt][k] = w[(tb0 + lt)*16 + k]; }
  __syncthreads();

  for (int e = tid; e < ZD*ZD; e += 256) {
    float v[16];
    #pragma unroll
    for (int u = 0; u < 16; ++u) v[u] = 0.f;
    #pragma unroll 4
    for (int k = 0; k < 16; ++k) {
      float a = AK[k*ZD*ZD + e];
      #pragma unroll
      for (int u = 0; u < 16; ++u) v[u] += wl[u][k] * a;
    }
    #pragma unroll
    for (int u = 0; u < 16; ++u) matA[(size_t)(tb0+u)*(ZD*ZD) + e] = v[u];
  }
  for (int e = tid; e < AD*ZD; e += 256) {
    float v[16];
    #pragma unroll
    for (int u = 0; u < 16; ++u) v[u] = 0.f;
    #pragma unroll 4
    for (int k = 0; k < 16; ++k) {
      float a = CK[k*AD*ZD + e];
      #pragma unroll
      for (int u = 0; u < 16; ++u) v[u] += wl[u][k] * a;
    }
    #pragma unroll
    for (int u = 0; u < 16; ++u) matC[(size_t)(tb0+u)*(AD*ZD) + e] = v[u];
  }
}

#define FMA4(accrow, a, bv) { accrow[0] += (a)*(bv).x; accrow[1] += (a)*(bv).y; accrow[2] += (a)*(bv).z; accrow[3] += (a)*(bv).w; }

// ============ Kalman filter: one block per batch, 256 threads ============
__global__ __launch_bounds__(256) void kalman_kernel(
    const float* __restrict__ as_, const float* __restrict__ ws,
    float* __restrict__ out)
{
  const int b = blockIdx.x, tid = threadIdx.x;
  const float* Qm = ws + WS_Q;
  const float* Rm = ws + WS_R;
  const float* matA = out + OUT_MATA;
  const float* matC = out + OUT_MATC;
  float* means  = out + OUT_MEANS;
  float* covs   = out + OUT_COVS;
  float* nmeans = out + OUT_NMEANS;
  float* ncovs  = out + OUT_NCOVS;

  __shared__ __align__(16) float covp[ZD*ZD];     // 4096
  __shared__ __align__(16) float Al[ZD*65];       // 4160 (A, stride 65)
  __shared__ __align__(16) float xbuf[7424];      // phase-a: Cm/CP/Smat/KT ; phase-b: tmp
  __shared__ float meanp[ZD];
  __shared__ float meant[ZD];
  __shared__ float innov[AD];

  float* Cm   = xbuf;           // [32][68]
  float* CPm  = xbuf + 2176;    // [32][64]
  float* Smat = xbuf + 4224;    // [32][36]
  float* KT   = xbuf + 5376;    // [32][64]
  float* tmp  = xbuf;           // [64][68]  (phase-b, aliases dead Cm/CP/Smat)

  for (int e = tid; e < ZD*ZD; e += 256) covp[e] = ((e>>6) == (e&63)) ? 1.f : 0.f;
  if (tid < ZD) meanp[tid] = 0.f;
  __syncthreads();

  for (int t = 0; t < T_LEN; ++t) {
    const int tb = t*B_SZ + b;
    // ---- stage A (stride 65) and C (stride 68)
    {
      const float* Ag = matA + (size_t)tb*ZD*ZD;
      for (int e = tid; e < ZD*ZD; e += 256) Al[(e>>6)*65 + (e&63)] = Ag[e];
      const float* Cg = matC + (size_t)tb*AD*ZD;
      for (int e = tid; e < AD*ZD; e += 256) Cm[(e>>6)*68 + (e&63)] = Cg[e];
    }
    __syncthreads();
    // ---- innov = a_t - C meanp ; CP = C @ covp
    if (tid < 32) {
      float s = as_[(size_t)tb*AD + tid];
      for (int k = 0; k < ZD; ++k) s -= Cm[tid*68 + k] * meanp[k];
      innov[tid] = s;
    }
    {
      const int tx = tid & 15, ty = tid >> 4;   // ty 0..15 -> 2 rows each
      const int i0 = ty*2, j0 = tx*4;
      float acc0[4] = {0,0,0,0}, acc1[4] = {0,0,0,0};
      for (int k = 0; k < ZD; ++k) {
        const float4 bv = *(const float4*)&covp[k*ZD + j0];
        const float a0 = Cm[(i0+0)*68 + k];
        const float a1 = Cm[(i0+1)*68 + k];
        FMA4(acc0, a0, bv);
        FMA4(acc1, a1, bv);
      }
      *(float4*)&CPm[(i0+0)*ZD + j0] = make_float4(acc0[0],acc0[1],acc0[2],acc0[3]);
      *(float4*)&CPm[(i0+1)*ZD + j0] = make_float4(acc1[0],acc1[1],acc1[2],acc1[3]);
    }
    __syncthreads();
    // ---- S = CP @ C^T + R
    {
      const int i = tid >> 3, j0 = (tid & 7)*4;
      float a0=0.f,a1=0.f,a2=0.f,a3=0.f;
      for (int k = 0; k < ZD; ++k) {
        const float cp = CPm[i*ZD + k];
        a0 += cp * Cm[(j0+0)*68 + k];
        a1 += cp * Cm[(j0+1)*68 + k];
        a2 += cp * Cm[(j0+2)*68 + k];
        a3 += cp * Cm[(j0+3)*68 + k];
      }
      Smat[i*36 + j0+0] = a0 + Rm[i*32 + j0+0];
      Smat[i*36 + j0+1] = a1 + Rm[i*32 + j0+1];
      Smat[i*36 + j0+2] = a2 + Rm[i*32 + j0+2];
      Smat[i*36 + j0+3] = a3 + Rm[i*32 + j0+3];
    }
    __syncthreads();
    // ---- Cholesky S = L L^T : lanes 0..31 own rows in registers, shfl broadcasts
    if (tid < 32) {
      float Lr[32];
      #pragma unroll
      for (int j = 0; j < 32; ++j) Lr[j] = Smat[tid*36 + j];
      #pragma unroll
      for (int k = 0; k < 32; ++k) {
        const float piv = __shfl(Lr[k], k);
        const float lkk = sqrtf(piv);
        const float lik = Lr[k] / lkk;
        #pragma unroll
        for (int j = k+1; j < 32; ++j) {
          const float ljk = __shfl(lik, j);
          Lr[j] -= lik * ljk;
        }
        Lr[k] = lik;
      }
      #pragma unroll
      for (int j = 0; j < 32; ++j) if (j <= tid) Smat[tid*36 + j] = Lr[j];
    }
    __syncthreads();
    // ---- solve S * KT = CP (KT = K^T, [32][64]); lanes 0..63 one column each; also mean_t
    if (tid < 64) {
      const int c = tid;
      float y[32];
      #pragma unroll
      for (int i = 0; i < 32; ++i) {
        float s = CPm[i*ZD + c];
        #pragma unroll
        for (int j = 0; j < i; ++j) s -= Smat[i*36 + j] * y[j];
        y[i] = s / Smat[i*36 + i];
      }
      #pragma unroll
      for (int i = 31; i >= 0; --i) {
        float s = y[i];
        #pragma unroll
        for (int j = i+1; j < 32; ++j) s -= Smat[j*36 + i] * y[j];
        y[i] = s / Smat[i*36 + i];
        KT[i*ZD + c] = y[i];
      }
      float s = meanp[c];
      #pragma unroll
      for (int a = 0; a < 32; ++a) s += y[a] * innov[a];
      meant[c] = s;
    }
    __syncthreads();
    // ---- M = covp - K @ CP (in place; K[i][a] = KT[a][i])
    {
      const int tx = tid & 15, ty = tid >> 4;
      const int i0 = ty*4, j0 = tx*4;
      float acc[4][4] = {};
      for (int a = 0; a < 32; ++a) {
        const float4 av = *(const float4*)&KT[a*ZD + i0];
        const float4 bv = *(const float4*)&CPm[a*ZD + j0];
        FMA4(acc[0], av.x, bv);
        FMA4(acc[1], av.y, bv);
        FMA4(acc[2], av.z, bv);
        FMA4(acc[3], av.w, bv);
      }
      #pragma unroll
      for (int ii = 0; ii < 4; ++ii) {
        float4 cv = *(const float4*)&covp[(i0+ii)*ZD + j0];
        cv.x -= acc[ii][0]; cv.y -= acc[ii][1]; cv.z -= acc[ii][2]; cv.w -= acc[ii][3];
        *(float4*)&covp[(i0+ii)*ZD + j0] = cv;
      }
    }
    __syncthreads();
    // ---- sym(covp) ; mean outputs and mean_next
    if (tid < ZD) {
      float s = 0.f;
      for (int k = 0; k < ZD; ++k) s += Al[tid*65 + k] * meant[k];
      means [(size_t)tb*ZD + tid] = meant[tid];
      nmeans[(size_t)tb*ZD + tid] = s;
      meanp[tid] = s;
    }
    for (int e = tid; e < ZD*ZD; e += 256) {
      const int i = e >> 6, j = e & 63;
      if (i < j) {
        const float u = covp[e], v = covp[j*ZD + i];
        const float m = 0.5f*(u + v);
        covp[e] = m; covp[j*ZD + i] = m;
      }
    }
    __syncthreads();
    // ---- write cov_t ; tmp = A @ cov_t
    {
      float* cg = covs + (size_t)tb*ZD*ZD;
      for (int e = tid; e < ZD*ZD; e += 256) cg[e] = covp[e];
    }
    {
      const int tx = tid & 15, ty = tid >> 4;
      const int i0 = ty*4, j0 = tx*4;
      float acc[4][4] = {};
      for (int k = 0; k < ZD; ++k) {
        const float4 bv = *(const float4*)&covp[k*ZD + j0];
        const float a0 = Al[(i0+0)*65 + k];
        const float a1 = Al[(i0+1)*65 + k];
        const float a2 = Al[(i0+2)*65 + k];
        const float a3 = Al[(i0+3)*65 + k];
        FMA4(acc[0], a0, bv);
        FMA4(acc[1], a1, bv);
        FMA4(acc[2], a2, bv);
        FMA4(acc[3], a3, bv);
      }
      #pragma unroll
      for (int ii = 0; ii < 4; ++ii)
        *(float4*)&tmp[(i0+ii)*68 + j0] = make_float4(acc[ii][0],acc[ii][1],acc[ii][2],acc[ii][3]);
    }
    __syncthreads();
    // ---- covnext = tmp @ A^T + Q (into covp)
    {
      const int tx = tid & 15, ty = tid >> 4;
      const int i0 = ty*4, j0 = tx*4;
      float acc[4][4] = {};
      for (int k = 0; k < ZD; ++k) {
        const float a0 = tmp[(i0+0)*68 + k];
        const float a1 = tmp[(i0+1)*68 + k];
        const float a2 = tmp[(i0+2)*68 + k];
        const float a3 = tmp[(i0+3)*68 + k];
        const float b0 = Al[(j0+0)*65 + k];
        const float b1 = Al[(j0+1)*65 + k];
        const float b2 = Al[(j0+2)*65 + k];
        const float b3 = Al[(j0+3)*65 + k];
        acc[0][0]+=a0*b0; acc[0][1]+=a0*b1; acc[0][2]+=a0*b2; acc[0][3]+=a0*b3;
        acc[1][0]+=a1*b0; acc[1][1]+=a1*b1; acc[1][2]+=a1*b2; acc[1][3]+=a1*b3;
        acc[2][0]+=a2*b0; acc[2][1]+=a2*b1; acc[2][2]+=a2*b2; acc[2][3]+=a2*b3;
        acc[3][0]+=a3*b0; acc[3][1]+=a3*b1; acc[3][2]+=a3*b2; acc[3][3]+=a3*b3;
      }
      #pragma unroll
      for (int ii = 0; ii < 4; ++ii) {
        const float4 qv = *(const float4*)&Qm[(i0+ii)*ZD + j0];
        *(float4*)&covp[(i0+ii)*ZD + j0] =
          make_float4(acc[ii][0]+qv.x, acc[ii][1]+qv.y, acc[ii][2]+qv.z, acc[ii][3]+qv.w);
      }
    }
    __syncthreads();
    // ---- sym(covnext)
    for (int e = tid; e < ZD*ZD; e += 256) {
      const int i = e >> 6, j = e & 63;
      if (i < j) {
        const float u = covp[e], v = covp[j*ZD + i];
        const float m = 0.5f*(u + v);
        covp[e] = m; covp[j*ZD + i] = m;
      }
    }
    __syncthreads();
    // ---- write cov_next (covp persists as next prior)
    {
      float* cg = ncovs + (size_t)tb*ZD*ZD;
      for (int e = tid; e < ZD*ZD; e += 256) cg[e] = covp[e];
    }
    // next-iter staging only writes Al/xbuf (disjoint from covp) before the barrier
  }
}

extern "C" void kernel_launch(void* const* d_in, const int* in_sizes, int n_in,
                              void* d_out, int out_size, void* d_ws, size_t ws_size,
                              hipStream_t stream) {
  const float* as_  = (const float*)d_in[0];
  const float* AK   = (const float*)d_in[1];
  const float* CK   = (const float*)d_in[2];
  const float* QL   = (const float*)d_in[3];
  const float* RL   = (const float*)d_in[4];
  const float* linW = (const float*)d_in[5];
  const float* linb = (const float*)d_in[6];
  const float* Wih0 = (const float*)d_in[7];
  const float* Whh0 = (const float*)d_in[8];
  const float* bih0 = (const float*)d_in[9];
  const float* bhh0 = (const float*)d_in[10];
  const float* Wih1 = (const float*)d_in[11];
  const float* Whh1 = (const float*)d_in[12];
  const float* bih1 = (const float*)d_in[13];
  const float* bhh1 = (const float*)d_in[14];
  float* out = (float*)d_out;
  float* ws  = (float*)d_ws;

  prep_kernel<<<856, 256, 0, stream>>>(Wih0, Whh0, bih0, bhh0,
                                       Wih1, Whh1, bih1, bhh1, QL, RL, ws);
  lstm_kernel<<<B_SZ, 512, 0, stream>>>(as_, ws, linW, linb, ws + WS_W);
  mix_kernel<<<(T_LEN*B_SZ)/16, 256, 0, stream>>>(ws + WS_W, AK, CK, out);
  kalman_kernel<<<B_SZ, 256, 0, stream>>>(as_, ws, out);
}